// Round 1
// baseline (148.704 us; speedup 1.0000x reference)
//
#include <hip/hip_runtime.h>

#define N_DET 128
#define N_T   2048
#define NPIX  65536   // 256*256
#define BATCH 4

// Kernel 1: transpose sino (B, N_DET, N_T) -> ws (N_DET, N_T, B) so the 4
// batches' samples at one (d,t) are a single contiguous float4 (one dwordx4
// gather serves all 4 batches).
__global__ __launch_bounds__(256) void sino_transpose_kernel(
    const float* __restrict__ sino, float* __restrict__ wsT) {
  int idx = blockIdx.x * blockDim.x + threadIdx.x;   // idx = d*N_T + t
  float4 v;
  v.x = sino[0 * N_DET * N_T + idx];
  v.y = sino[1 * N_DET * N_T + idx];
  v.z = sino[2 * N_DET * N_T + idx];
  v.w = sino[3 * N_DET * N_T + idx];
  reinterpret_cast<float4*>(wsT)[idx] = v;
}

// Kernel 2: one wave (64 lanes) per pixel. Lane l handles detectors 2l, 2l+1.
// lut read is fully coalesced (lane l reads float4 = two (tof,alpha) pairs).
// Gathers: 2 dwordx4 per (lane, det) in transposed layout (4 batches at once).
template <bool TRANSPOSED>
__global__ __launch_bounds__(256) void das_kernel(
    const float* __restrict__ lut, const float* __restrict__ S,
    float* __restrict__ out) {
  const int lane = threadIdx.x & 63;
  const int p = blockIdx.x * 4 + (threadIdx.x >> 6);  // pixel id, 4 waves/block

  // lut segment for pixel p: 128 (tof, alpha) pairs = 256 floats = 1 KB.
  float4 lv = reinterpret_cast<const float4*>(lut + (size_t)p * 2 * N_DET)[lane];

  float acc0 = 0.f, acc1 = 0.f, acc2 = 0.f, acc3 = 0.f;
  float wsum = 0.f;

#pragma unroll
  for (int j = 0; j < 2; ++j) {
    const int d = 2 * lane + j;
    const float tof = j ? lv.z : lv.x;
    const float a   = j ? lv.w : lv.y;

    const float kf  = floorf(tof);
    const bool valid = (kf >= 0.0f) && (kf < (float)(N_T - 1));
    const float kcl = fminf(fmaxf(kf, 0.0f), (float)(N_T - 2));
    const int k0 = (int)kcl;

    // Hann apodization, computed in-register (matches fp32 reference ~1 ulp).
    const float apd =
        0.5f - 0.5f * cosf(6.28318530717958647692f * (1.0f / (float)(N_DET - 1)) * (float)d);
    wsum += apd;                       // norm is valid-independent (per reference)
    const float w = valid ? apd : 0.0f;
    const float om = 1.0f - a;

    if (TRANSPOSED) {
      const float4* row = reinterpret_cast<const float4*>(S) + (size_t)d * N_T;
      const float4 s0 = row[k0];
      const float4 s1 = row[k0 + 1];
      acc0 += w * (om * s0.x + a * s1.x);
      acc1 += w * (om * s0.y + a * s1.y);
      acc2 += w * (om * s0.z + a * s1.z);
      acc3 += w * (om * s0.w + a * s1.w);
    } else {
      const float* row = S + (size_t)d * N_T + k0;
      acc0 += w * (om * row[0 * N_DET * N_T] + a * row[0 * N_DET * N_T + 1]);
      acc1 += w * (om * row[1 * N_DET * N_T] + a * row[1 * N_DET * N_T + 1]);
      acc2 += w * (om * row[2 * N_DET * N_T] + a * row[2 * N_DET * N_T + 1]);
      acc3 += w * (om * row[3 * N_DET * N_T] + a * row[3 * N_DET * N_T + 1]);
    }
  }

  // Butterfly reduction across the 64-lane wave (5 values).
#pragma unroll
  for (int off = 32; off > 0; off >>= 1) {
    acc0 += __shfl_xor(acc0, off);
    acc1 += __shfl_xor(acc1, off);
    acc2 += __shfl_xor(acc2, off);
    acc3 += __shfl_xor(acc3, off);
    wsum += __shfl_xor(wsum, off);
  }

  if (lane == 0) {
    const float inv = 1.0f / fmaxf(wsum, 1.17549435e-38f);
    out[0 * NPIX + p] = acc0 * inv;
    out[1 * NPIX + p] = acc1 * inv;
    out[2 * NPIX + p] = acc2 * inv;
    out[3 * NPIX + p] = acc3 * inv;
  }
}

extern "C" void kernel_launch(void* const* d_in, const int* in_sizes, int n_in,
                              void* d_out, int out_size, void* d_ws, size_t ws_size,
                              hipStream_t stream) {
  const float* sino = (const float*)d_in[0];  // (B,1,N_DET,N_T) fp32
  const float* lut  = (const float*)d_in[1];  // (NY,NX,N_DET,2) fp32
  float* out = (float*)d_out;                 // (B,1,NY,NX) fp32

  const size_t need = (size_t)N_DET * N_T * BATCH * sizeof(float);  // 4 MB
  if (ws_size >= need) {
    float* wsT = (float*)d_ws;
    sino_transpose_kernel<<<(N_DET * N_T) / 256, 256, 0, stream>>>(sino, wsT);
    das_kernel<true><<<NPIX / 4, 256, 0, stream>>>(lut, wsT, out);
  } else {
    das_kernel<false><<<NPIX / 4, 256, 0, stream>>>(lut, sino, out);
  }
}

// Round 2
// 134.282 us; speedup vs baseline: 1.1074x; 1.1074x over previous
//
#include <hip/hip_runtime.h>
#include <hip/hip_fp16.h>

#define N_DET 128
#define N_T   2048
#define NPIX  65536   // 256*256
#define NBATCH 4

// Kernel 1: transpose+pack sino (B, N_DET, N_T) fp32 -> ws (N_DET, N_T) of
// 16-byte records: { s_t[b0..b3], s_{t+1}[b0..b3] } as 8 fp16.
// One aligned dwordx4 gather then serves BOTH interpolation taps for all 4
// batches (halves gather instruction count and L2 line traffic vs fp32 float4).
__global__ __launch_bounds__(256) void sino_pack_kernel(
    const float* __restrict__ sino, float4* __restrict__ wsT) {
  const int idx = blockIdx.x * blockDim.x + threadIdx.x;  // idx = d*N_T + t
  const int t = idx & (N_T - 1);
  const int idx1 = (t < N_T - 1) ? idx + 1 : idx;         // clamp (unused tap)
  __half h[8];
#pragma unroll
  for (int b = 0; b < NBATCH; ++b) {
    h[b]     = __float2half(sino[b * N_DET * N_T + idx]);
    h[b + 4] = __float2half(sino[b * N_DET * N_T + idx1]);
  }
  wsT[idx] = *reinterpret_cast<const float4*>(h);
}

// Kernel 2: one wave per pixel; lane l handles detectors 2l, 2l+1.
// lut read coalesced (float4 per lane = two (tof,alpha) pairs).
// One 16 B gather per (lane, det) in packed layout.
__global__ __launch_bounds__(256) void das_packed_kernel(
    const float* __restrict__ lut, const float4* __restrict__ S,
    float* __restrict__ out) {
  const int lane = threadIdx.x & 63;
  const int p = blockIdx.x * 4 + (threadIdx.x >> 6);  // pixel id, 4 waves/block

  const float4 lv =
      reinterpret_cast<const float4*>(lut + (size_t)p * 2 * N_DET)[lane];

  float acc0 = 0.f, acc1 = 0.f, acc2 = 0.f, acc3 = 0.f;
  float wsum = 0.f;

#pragma unroll
  for (int j = 0; j < 2; ++j) {
    const int d = 2 * lane + j;
    const float tof = j ? lv.z : lv.x;
    const float a   = j ? lv.w : lv.y;

    const float kf = floorf(tof);
    const bool valid = (kf >= 0.0f) && (kf < (float)(N_T - 1));
    const float kcl = fminf(fmaxf(kf, 0.0f), (float)(N_T - 2));
    const int k0 = (int)kcl;

    const float apd =
        0.5f - 0.5f * cosf(6.28318530717958647692f *
                           (1.0f / (float)(N_DET - 1)) * (float)d);
    wsum += apd;
    const float w = valid ? apd : 0.0f;
    const float om = 1.0f - a;

    const float4 v = S[(size_t)d * N_T + k0];  // 16B: s0[4b] + s1[4b] fp16
    const __half2* hp = reinterpret_cast<const __half2*>(&v);
    const float2 s0a = __half22float2(hp[0]);  // t:   b0,b1
    const float2 s0b = __half22float2(hp[1]);  // t:   b2,b3
    const float2 s1a = __half22float2(hp[2]);  // t+1: b0,b1
    const float2 s1b = __half22float2(hp[3]);  // t+1: b2,b3

    acc0 += w * (om * s0a.x + a * s1a.x);
    acc1 += w * (om * s0a.y + a * s1a.y);
    acc2 += w * (om * s0b.x + a * s1b.x);
    acc3 += w * (om * s0b.y + a * s1b.y);
  }

#pragma unroll
  for (int off = 32; off > 0; off >>= 1) {
    acc0 += __shfl_xor(acc0, off);
    acc1 += __shfl_xor(acc1, off);
    acc2 += __shfl_xor(acc2, off);
    acc3 += __shfl_xor(acc3, off);
    wsum += __shfl_xor(wsum, off);
  }

  if (lane == 0) {
    const float inv = 1.0f / fmaxf(wsum, 1.17549435e-38f);
    out[0 * NPIX + p] = acc0 * inv;
    out[1 * NPIX + p] = acc1 * inv;
    out[2 * NPIX + p] = acc2 * inv;
    out[3 * NPIX + p] = acc3 * inv;
  }
}

// Fallback (no workspace): direct fp32 gather from original layout.
__global__ __launch_bounds__(256) void das_fallback_kernel(
    const float* __restrict__ lut, const float* __restrict__ S,
    float* __restrict__ out) {
  const int lane = threadIdx.x & 63;
  const int p = blockIdx.x * 4 + (threadIdx.x >> 6);

  const float4 lv =
      reinterpret_cast<const float4*>(lut + (size_t)p * 2 * N_DET)[lane];

  float acc0 = 0.f, acc1 = 0.f, acc2 = 0.f, acc3 = 0.f;
  float wsum = 0.f;

#pragma unroll
  for (int j = 0; j < 2; ++j) {
    const int d = 2 * lane + j;
    const float tof = j ? lv.z : lv.x;
    const float a   = j ? lv.w : lv.y;
    const float kf = floorf(tof);
    const bool valid = (kf >= 0.0f) && (kf < (float)(N_T - 1));
    const float kcl = fminf(fmaxf(kf, 0.0f), (float)(N_T - 2));
    const int k0 = (int)kcl;
    const float apd =
        0.5f - 0.5f * cosf(6.28318530717958647692f *
                           (1.0f / (float)(N_DET - 1)) * (float)d);
    wsum += apd;
    const float w = valid ? apd : 0.0f;
    const float om = 1.0f - a;
    const float* row = S + (size_t)d * N_T + k0;
    acc0 += w * (om * row[0 * N_DET * N_T] + a * row[0 * N_DET * N_T + 1]);
    acc1 += w * (om * row[1 * N_DET * N_T] + a * row[1 * N_DET * N_T + 1]);
    acc2 += w * (om * row[2 * N_DET * N_T] + a * row[2 * N_DET * N_T + 1]);
    acc3 += w * (om * row[3 * N_DET * N_T] + a * row[3 * N_DET * N_T + 1]);
  }

#pragma unroll
  for (int off = 32; off > 0; off >>= 1) {
    acc0 += __shfl_xor(acc0, off);
    acc1 += __shfl_xor(acc1, off);
    acc2 += __shfl_xor(acc2, off);
    acc3 += __shfl_xor(acc3, off);
    wsum += __shfl_xor(wsum, off);
  }

  if (lane == 0) {
    const float inv = 1.0f / fmaxf(wsum, 1.17549435e-38f);
    out[0 * NPIX + p] = acc0 * inv;
    out[1 * NPIX + p] = acc1 * inv;
    out[2 * NPIX + p] = acc2 * inv;
    out[3 * NPIX + p] = acc3 * inv;
  }
}

extern "C" void kernel_launch(void* const* d_in, const int* in_sizes, int n_in,
                              void* d_out, int out_size, void* d_ws, size_t ws_size,
                              hipStream_t stream) {
  const float* sino = (const float*)d_in[0];  // (B,1,N_DET,N_T) fp32
  const float* lut  = (const float*)d_in[1];  // (NY,NX,N_DET,2) fp32
  float* out = (float*)d_out;                 // (B,1,NY,NX) fp32

  const size_t need = (size_t)N_DET * N_T * sizeof(float4);  // 4 MB
  if (ws_size >= need) {
    float4* wsT = (float4*)d_ws;
    sino_pack_kernel<<<(N_DET * N_T) / 256, 256, 0, stream>>>(sino, wsT);
    das_packed_kernel<<<NPIX / 4, 256, 0, stream>>>(lut, wsT, out);
  } else {
    das_fallback_kernel<<<NPIX / 4, 256, 0, stream>>>(lut, sino, out);
  }
}